// Round 22
// baseline (54.905 us; speedup 1.0000x reference)
//
#include <hip/hip_runtime.h>
#include <cstdint>

typedef __attribute__((ext_vector_type(8))) short bf16x8;
typedef __attribute__((ext_vector_type(4))) float f32x4;

#if __has_builtin(__builtin_amdgcn_exp2f)
#define EXP2F(x) __builtin_amdgcn_exp2f(x)
#else
#define EXP2F(x) exp2f(x)
#endif
#if __has_builtin(__builtin_amdgcn_rcpf)
#define RCPF(x) __builtin_amdgcn_rcpf(x)
#else
#define RCPF(x) (1.0f/(x))
#endif

#define C2LOG2E 2.885390081777927f   // 2*log2(e)
#define LOG2E   1.4426950408889634f

__device__ __forceinline__ unsigned int f2bf(float f) {
    union { float f; unsigned int u; } v; v.f = f;
    return ((v.u + 0x7FFFu + ((v.u >> 16) & 1u)) >> 16);
}
__device__ __forceinline__ float bf2f(unsigned short h) {
    union { unsigned int u; float f; } v; v.u = ((unsigned int)h) << 16; return v.f;
}

// ---- prep: Xb bf16; XT bf16 (d-major); Wt f32 (W_ap^T); Wpab/Wpob bf16; BN consts ----
__global__ void prep_kernel(const float* __restrict__ x, const float* __restrict__ W_ap,
                            const float* __restrict__ W_pa, const float* __restrict__ W_po,
                            const float* __restrict__ b_pa, const float* __restrict__ b_po,
                            const float* __restrict__ gma, const float* __restrict__ bta,
                            const float* __restrict__ rmean, const float* __restrict__ rvar,
                            unsigned short* __restrict__ Xb, unsigned short* __restrict__ XT,
                            float* __restrict__ Wt,
                            unsigned short* __restrict__ Wpab, unsigned short* __restrict__ Wpob,
                            float* __restrict__ bnA, float* __restrict__ bnBB) {
    int t = blockIdx.x * 256 + threadIdx.x;   // 32768 threads, 8 elems each
    const float* src = x + (size_t)t * 8;
    float4 a = *(const float4*)(src);
    float4 b = *(const float4*)(src + 4);
    unsigned int p0 = f2bf(a.x) | (f2bf(a.y) << 16);
    unsigned int p1 = f2bf(a.z) | (f2bf(a.w) << 16);
    unsigned int p2 = f2bf(b.x) | (f2bf(b.y) << 16);
    unsigned int p3 = f2bf(b.z) | (f2bf(b.w) << 16);
    *(int4*)(Xb + (size_t)t * 8) = make_int4((int)p0, (int)p1, (int)p2, (int)p3);
    // XT[b][d][j]
    {
        int bb = t >> 12;
        int bj = (t >> 3) & 511;
        int d0 = (t & 7) * 8;
        unsigned short* xt = XT + (size_t)bb * (64 * 512) + bj;
        unsigned short e[8] = {(unsigned short)(p0 & 0xffff), (unsigned short)(p0 >> 16),
                               (unsigned short)(p1 & 0xffff), (unsigned short)(p1 >> 16),
                               (unsigned short)(p2 & 0xffff), (unsigned short)(p2 >> 16),
                               (unsigned short)(p3 & 0xffff), (unsigned short)(p3 >> 16)};
        #pragma unroll
        for (int k = 0; k < 8; ++k) xt[(size_t)(d0 + k) * 512] = e[k];
    }
    if (t < 64 * 64) {
        int src_i = (t & 63) * 64 + (t >> 6);   // [d][o] -> [o][d]
        Wt[t]   = W_ap[src_i];
        Wpab[t] = (unsigned short)f2bf(W_pa[src_i]);
        Wpob[t] = (unsigned short)f2bf(W_po[src_i]);
    }
    if (t < 64) {
        float A = gma[t] * rsqrtf(rvar[t] + 1e-5f);
        bnA[t]  = A;
        bnBB[t] = (b_pa[t] + b_po[t] - rmean[t]) * A + bta[t];
    }
}

// ---- A: scores, cyclic triangle (R18 coverage), 16-ROW BLOCKS + LDS-STAGED
// MIRROR FLUSH. R15 vs R18 accounting shows the 2B Ecol scatter costs ~15us:
// 16 scattered stores/tile/row = ~1M sub-line L2 write transactions. Fix: the
// block's 16 rows (16 waves, identical windows) stage e into LDS per tile;
// after one barrier, wave 0 writes E[j][i0..i0+15] as two 16B stores (16x
// fewer transactions, line-shaped). Double-buffered stage; row writes stay
// per-wave contiguous. Same 4 waves/SIMD (1 block/CU), grid fully resident.
__global__ __launch_bounds__(1024, 1) void score_kernel(
    const float* __restrict__ x, const float* __restrict__ b_ap, const float* __restrict__ att_w,
    const unsigned short* __restrict__ Xb, const float* __restrict__ Wt,
    unsigned short* __restrict__ E)
{
    __shared__ unsigned short stage[2][16][16];   // [buf][j-local][row]

    const int t  = threadIdx.x;
    const int l  = t & 63;
    const int w  = t >> 6;                    // 0..15 = row within strip
    const int bid = blockIdx.x;               // 256 blocks
    const int b   = bid & 7;                  // XCD k <-> batch k
    const int strip = bid >> 3;               // 0..31
    const int i0  = strip * 16;
    const int i   = i0 + w;
    const int lm = l & 15;
    const int lq = l >> 4;
    const unsigned short* __restrict__ Xg = Xb + (size_t)b * (512 * 64);
    const float* __restrict__ xi = x + ((size_t)b * 512 + i) * 64;

    // ---- A-fragments (W_i^T), pre-scaled by 2*log2(e) ----
    bf16x8 af[8];
    #pragma unroll
    for (int ks = 0; ks < 2; ++ks) {
        float4 xc0 = *(const float4*)(xi + ks * 32 + lq * 8);
        float4 xc1 = *(const float4*)(xi + ks * 32 + lq * 8 + 4);
        xc0.x *= C2LOG2E; xc0.y *= C2LOG2E; xc0.z *= C2LOG2E; xc0.w *= C2LOG2E;
        xc1.x *= C2LOG2E; xc1.y *= C2LOG2E; xc1.z *= C2LOG2E; xc1.w *= C2LOG2E;
        #pragma unroll
        for (int of = 0; of < 4; ++of) {
            const float* wr = Wt + (of * 16 + lm) * 64 + ks * 32 + lq * 8;
            float4 w0 = *(const float4*)(wr);
            float4 w1 = *(const float4*)(wr + 4);
            unsigned int p0 = f2bf(w0.x * xc0.x) | (f2bf(w0.y * xc0.y) << 16);
            unsigned int p1 = f2bf(w0.z * xc0.z) | (f2bf(w0.w * xc0.w) << 16);
            unsigned int p2 = f2bf(w1.x * xc1.x) | (f2bf(w1.y * xc1.y) << 16);
            unsigned int p3 = f2bf(w1.z * xc1.z) | (f2bf(w1.w * xc1.w) << 16);
            int4 pk = make_int4((int)p0, (int)p1, (int)p2, (int)p3);
            af[of * 2 + ks] = *reinterpret_cast<bf16x8*>(&pk);
        }
    }

    // ---- per-lane o-consts; bias folded into MFMA C-init ----
    float n2a[16];
    f32x4 binit[4];
    float asum = 0.f, aabs = 0.f;
    #pragma unroll
    for (int of = 0; of < 4; ++of) {
        #pragma unroll
        for (int r = 0; r < 4; ++r) {
            int o = of * 16 + lq * 4 + r;
            float a = att_w[o];
            n2a[of * 4 + r] = -2.f * a;
            binit[of][r]    = C2LOG2E * b_ap[o];
            asum += a;
            aabs += fabsf(a);
        }
    }
    asum += __shfl_xor(asum, 16); asum += __shfl_xor(asum, 32);
    aabs += __shfl_xor(aabs, 16); aabs += __shfl_xor(aabs, 32);
    const float coff = (asum - aabs) * LOG2E;  // e_j = exp2(ss*lg2e + coff)

    const int smax = (strip < 16) ? 17 : 16;   // it0 == strip for all rows here
    unsigned short* __restrict__ Erow = E + ((size_t)b * 512 + i) * 512;
    unsigned short* __restrict__ Ecb  = E + (size_t)b * (512 * 512);
    const unsigned short* xrow = Xg + lm * 64 + lq * 8;

    for (int s = 0; s < smax; ++s) {
        const int jt = (strip + s) & 31;
        bf16x8 b0 = *(const bf16x8*)(xrow + jt * 1024);
        bf16x8 b1 = *(const bf16x8*)(xrow + jt * 1024 + 32);
        f32x4 a0 = binit[0], a1 = binit[1], a2 = binit[2], a3 = binit[3];
        a0 = __builtin_amdgcn_mfma_f32_16x16x32_bf16(af[0], b0, a0, 0, 0, 0);
        a1 = __builtin_amdgcn_mfma_f32_16x16x32_bf16(af[2], b0, a1, 0, 0, 0);
        a2 = __builtin_amdgcn_mfma_f32_16x16x32_bf16(af[4], b0, a2, 0, 0, 0);
        a3 = __builtin_amdgcn_mfma_f32_16x16x32_bf16(af[6], b0, a3, 0, 0, 0);
        a0 = __builtin_amdgcn_mfma_f32_16x16x32_bf16(af[1], b1, a0, 0, 0, 0);
        a1 = __builtin_amdgcn_mfma_f32_16x16x32_bf16(af[3], b1, a1, 0, 0, 0);
        a2 = __builtin_amdgcn_mfma_f32_16x16x32_bf16(af[5], b1, a2, 0, 0, 0);
        a3 = __builtin_amdgcn_mfma_f32_16x16x32_bf16(af[7], b1, a3, 0, 0, 0);
        // flattened trans chains: 16 indep exp2 -> 16 indep rcp -> fma tree
        float ex[16], tt[16];
        #pragma unroll
        for (int r = 0; r < 4; ++r) {
            ex[r]      = EXP2F(a0[r]);
            ex[4 + r]  = EXP2F(a1[r]);
            ex[8 + r]  = EXP2F(a2[r]);
            ex[12 + r] = EXP2F(a3[r]);
        }
        #pragma unroll
        for (int k = 0; k < 16; ++k) tt[k] = RCPF(1.f + ex[k]);
        float q0 = 0.f, q1 = 0.f, q2 = 0.f, q3 = 0.f;
        #pragma unroll
        for (int r = 0; r < 4; ++r) {
            q0 = fmaf(n2a[r],      tt[r],      q0);
            q1 = fmaf(n2a[4 + r],  tt[4 + r],  q1);
            q2 = fmaf(n2a[8 + r],  tt[8 + r],  q2);
            q3 = fmaf(n2a[12 + r], tt[12 + r], q3);
        }
        float ss = (q0 + q1) + (q2 + q3);
        ss += __shfl_xor(ss, 16);
        ss += __shfl_xor(ss, 32);              // all lanes: full ss for j=jt*16+lm
        float ee = EXP2F(fmaf(ss, LOG2E, coff));
        unsigned short eb = (unsigned short)f2bf(ee);
        if (l < 16) {
            Erow[jt * 16 + l] = eb;            // contiguous row write (32B/tile/wave)
            stage[s & 1][l][w] = eb;           // stage for column flush
        }
        __syncthreads();                        // stage complete for this tile
        if (s != 0 && w == 0 && l < 16) {
            // flush E[jt*16+l][i0..i0+15] as two 16B stores
            const unsigned short* sp = &stage[s & 1][l][0];
            int4 v0 = *(const int4*)(sp);
            int4 v1 = *(const int4*)(sp + 8);
            unsigned short* dst = Ecb + (size_t)(jt * 16 + l) * 512 + i0;
            *(int4*)(dst)     = v0;
            *(int4*)(dst + 8) = v1;
        }
    }
}

// ---- B: agg GEMM (E @ X) + projections + BN + SELU, all MFMA. ----
__global__ __launch_bounds__(256, 4) void agg_kernel(
    const unsigned short* __restrict__ Xb, const unsigned short* __restrict__ XT,
    const unsigned short* __restrict__ E,
    const unsigned short* __restrict__ Wpab, const unsigned short* __restrict__ Wpob,
    const float* __restrict__ bnA, const float* __restrict__ bnBB,
    float* __restrict__ out)
{
    __shared__ float sInv[16];
    __shared__ unsigned short pA[16][72];   // bf16 unnormalized agg, +8 pad

    const int t  = threadIdx.x;
    const int l  = t & 63;
    const int w  = t >> 6;
    const int bid = blockIdx.x;
    const int b   = bid & 7;                  // same XCD<->batch map: E, XT L2-hot
    const int i0  = (bid >> 3) * 16;
    const int lm = l & 15;
    const int lq = l >> 4;

    // ---- GEMM 1: acc[i-off][d-off] = sum_j E[i][j] * X[j][d], d-tile = w ----
    const unsigned short* Erow  = E  + ((size_t)b * 512 + i0 + lm) * 512 + lq * 8;
    const unsigned short* xtrow = XT + (size_t)b * (64 * 512) + (w * 16 + lm) * 512 + lq * 8;
    f32x4 acc = (f32x4){0.f, 0.f, 0.f, 0.f};
    float den = 0.f;
    #pragma unroll
    for (int jc = 0; jc < 16; ++jc) {
        bf16x8 ae = *(const bf16x8*)(Erow + jc * 32);
        bf16x8 bx = *(const bf16x8*)(xtrow + jc * 32);
        acc = __builtin_amdgcn_mfma_f32_16x16x32_bf16(ae, bx, acc, 0, 0, 0);
        if (w == 0) {
            #pragma unroll
            for (int e = 0; e < 8; ++e) den += bf2f((unsigned short)ae[e]);
        }
    }
    if (w == 0) {
        den += __shfl_xor(den, 16);
        den += __shfl_xor(den, 32);
        if (l < 16) sInv[l] = RCPF(den);
    }
    #pragma unroll
    for (int r = 0; r < 4; ++r)
        pA[lq * 4 + r][w * 16 + lm] = (unsigned short)f2bf(acc[r]);
    __syncthreads();

    // ---- GEMM 2: h = inv[i] * (aggU @ W_pa) + (x @ W_po); o-tile = w ----
    bf16x8 af2[2], afx[2], bwa[2], bwo[2];
    #pragma unroll
    for (int kc = 0; kc < 2; ++kc) {
        af2[kc] = *(const bf16x8*)(&pA[lm][kc * 32 + lq * 8]);
        afx[kc] = *(const bf16x8*)(Xb + ((size_t)b * 512 + i0 + lm) * 64 + kc * 32 + lq * 8);
        bwa[kc] = *(const bf16x8*)(Wpab + (w * 16 + lm) * 64 + kc * 32 + lq * 8);
        bwo[kc] = *(const bf16x8*)(Wpob + (w * 16 + lm) * 64 + kc * 32 + lq * 8);
    }
    f32x4 a2a = (f32x4){0.f, 0.f, 0.f, 0.f};
    f32x4 a2x = (f32x4){0.f, 0.f, 0.f, 0.f};
    a2a = __builtin_amdgcn_mfma_f32_16x16x32_bf16(af2[0], bwa[0], a2a, 0, 0, 0);
    a2x = __builtin_amdgcn_mfma_f32_16x16x32_bf16(afx[0], bwo[0], a2x, 0, 0, 0);
    a2a = __builtin_amdgcn_mfma_f32_16x16x32_bf16(af2[1], bwa[1], a2a, 0, 0, 0);
    a2x = __builtin_amdgcn_mfma_f32_16x16x32_bf16(afx[1], bwo[1], a2x, 0, 0, 0);

    // ---- epilogue: BN (biases folded) + SELU ----
    const int o = w * 16 + lm;
    const float A  = bnA[o];
    const float BB = bnBB[o];
    const float alpha = 1.6732632423543772f, scale = 1.0507009873554805f;
    #pragma unroll
    for (int r = 0; r < 4; ++r) {
        int i = i0 + lq * 4 + r;
        float hv = fmaf(sInv[lq * 4 + r], a2a[r], a2x[r]);
        hv = fmaf(hv, A, BB);
        float neg = alpha * (EXP2F(hv * LOG2E) - 1.0f);
        out[((size_t)b * 512 + i) * 64 + o] = scale * (hv > 0.f ? hv : neg);
    }
}

extern "C" void kernel_launch(void* const* d_in, const int* in_sizes, int n_in,
                              void* d_out, int out_size, void* d_ws, size_t ws_size,
                              hipStream_t stream) {
    const float* x     = (const float*)d_in[0];
    const float* W_ap  = (const float*)d_in[1];
    const float* b_ap  = (const float*)d_in[2];
    const float* att_w = (const float*)d_in[3];
    const float* W_pa  = (const float*)d_in[4];
    const float* b_pa  = (const float*)d_in[5];
    const float* W_po  = (const float*)d_in[6];
    const float* b_po  = (const float*)d_in[7];
    const float* gma   = (const float*)d_in[8];
    const float* bta   = (const float*)d_in[9];
    const float* rmean = (const float*)d_in[10];
    const float* rvar  = (const float*)d_in[11];

    char* ws = (char*)d_ws;
    unsigned short* Xb   = (unsigned short*)ws;                 // 512 KB bf16 X
    unsigned short* XT   = (unsigned short*)(ws + 512 * 1024);  // 512 KB bf16 X^T (d-major)
    float* Wt            = (float*)(ws + 1024 * 1024);          // 16 KB W_ap^T f32
    unsigned short* Wpab = (unsigned short*)(ws + 1040 * 1024); // 8 KB W_pa^T bf16
    unsigned short* Wpob = (unsigned short*)(ws + 1048 * 1024); // 8 KB W_po^T bf16
    float* bnA           = (float*)(ws + 1056 * 1024);          // 256 B
    float* bnBB          = (float*)(ws + 1057 * 1024);          // 256 B
    unsigned short* E    = (unsigned short*)(ws + 1088 * 1024); // 4 MB bf16 E[b][i][j]
    float* out           = (float*)d_out;

    prep_kernel<<<128, 256, 0, stream>>>(x, W_ap, W_pa, W_po, b_pa, b_po, gma, bta,
                                         rmean, rvar, Xb, XT, Wt, Wpab, Wpob, bnA, bnBB);
    score_kernel<<<256, 1024, 0, stream>>>(x, b_ap, att_w, Xb, Wt, E);
    agg_kernel<<<256, 256, 0, stream>>>(Xb, XT, E, Wpab, Wpob, bnA, bnBB, out);
}

// Round 23
// 45.150 us; speedup vs baseline: 1.2161x; 1.2161x over previous
//
#include <hip/hip_runtime.h>
#include <cstdint>

typedef __attribute__((ext_vector_type(8))) short bf16x8;
typedef __attribute__((ext_vector_type(4))) float f32x4;

#if __has_builtin(__builtin_amdgcn_exp2f)
#define EXP2F(x) __builtin_amdgcn_exp2f(x)
#else
#define EXP2F(x) exp2f(x)
#endif
#if __has_builtin(__builtin_amdgcn_rcpf)
#define RCPF(x) __builtin_amdgcn_rcpf(x)
#else
#define RCPF(x) (1.0f/(x))
#endif

#define C2LOG2E 2.885390081777927f   // 2*log2(e)
#define LOG2E   1.4426950408889634f

__device__ __forceinline__ unsigned int f2bf(float f) {
    union { float f; unsigned int u; } v; v.f = f;
    return ((v.u + 0x7FFFu + ((v.u >> 16) & 1u)) >> 16);
}
__device__ __forceinline__ float bf2f(unsigned short h) {
    union { unsigned int u; float f; } v; v.u = ((unsigned int)h) << 16; return v.f;
}

// ---- prep: Xb bf16; XT bf16 (d-major); Wt f32 (W_ap^T); Wpab/Wpob bf16; BN consts ----
__global__ void prep_kernel(const float* __restrict__ x, const float* __restrict__ W_ap,
                            const float* __restrict__ W_pa, const float* __restrict__ W_po,
                            const float* __restrict__ b_pa, const float* __restrict__ b_po,
                            const float* __restrict__ gma, const float* __restrict__ bta,
                            const float* __restrict__ rmean, const float* __restrict__ rvar,
                            unsigned short* __restrict__ Xb, unsigned short* __restrict__ XT,
                            float* __restrict__ Wt,
                            unsigned short* __restrict__ Wpab, unsigned short* __restrict__ Wpob,
                            float* __restrict__ bnA, float* __restrict__ bnBB) {
    int t = blockIdx.x * 256 + threadIdx.x;   // 32768 threads, 8 elems each
    const float* src = x + (size_t)t * 8;
    float4 a = *(const float4*)(src);
    float4 b = *(const float4*)(src + 4);
    unsigned int p0 = f2bf(a.x) | (f2bf(a.y) << 16);
    unsigned int p1 = f2bf(a.z) | (f2bf(a.w) << 16);
    unsigned int p2 = f2bf(b.x) | (f2bf(b.y) << 16);
    unsigned int p3 = f2bf(b.z) | (f2bf(b.w) << 16);
    *(int4*)(Xb + (size_t)t * 8) = make_int4((int)p0, (int)p1, (int)p2, (int)p3);
    // XT[b][d][j]
    {
        int bb = t >> 12;
        int bj = (t >> 3) & 511;
        int d0 = (t & 7) * 8;
        unsigned short* xt = XT + (size_t)bb * (64 * 512) + bj;
        unsigned short e[8] = {(unsigned short)(p0 & 0xffff), (unsigned short)(p0 >> 16),
                               (unsigned short)(p1 & 0xffff), (unsigned short)(p1 >> 16),
                               (unsigned short)(p2 & 0xffff), (unsigned short)(p2 >> 16),
                               (unsigned short)(p3 & 0xffff), (unsigned short)(p3 >> 16)};
        #pragma unroll
        for (int k = 0; k < 8; ++k) xt[(size_t)(d0 + k) * 512] = e[k];
    }
    if (t < 64 * 64) {
        int src_i = (t & 63) * 64 + (t >> 6);   // [d][o] -> [o][d]
        Wt[t]   = W_ap[src_i];
        Wpab[t] = (unsigned short)f2bf(W_pa[src_i]);
        Wpob[t] = (unsigned short)f2bf(W_po[src_i]);
    }
    if (t < 64) {
        float A = gma[t] * rsqrtf(rvar[t] + 1e-5f);
        bnA[t]  = A;
        bnBB[t] = (b_pa[t] + b_po[t] - rmean[t]) * A + bta[t];
    }
}

// ---- A: scores, cyclic triangle, 16-row strip blocks, BARRIER-FREE tile loop
// + SINGLE-BARRIER bulk mirror flush. R21 proved the per-tile barrier kills
// wave skew (41us despite clean writes); here the 17-tile loop runs free
// (mirror values go to LDS), then ONE __syncthreads + bulk flush: 240-256
// threads each write E[j][i0..i0+15] as two 16B stores. Row writes stay
// per-wave contiguous. Same 4 waves/SIMD; 256 blocks = 1/CU, one generation.
__global__ __launch_bounds__(1024, 1) void score_kernel(
    const float* __restrict__ x, const float* __restrict__ b_ap, const float* __restrict__ att_w,
    const unsigned short* __restrict__ Xb, const float* __restrict__ Wt,
    unsigned short* __restrict__ E)
{
    __shared__ unsigned short stage[17][16][16];   // [s][j-local][row] = 8.7 KB

    const int t  = threadIdx.x;
    const int l  = t & 63;
    const int w  = t >> 6;                    // 0..15 = row within strip
    const int bid = blockIdx.x;               // 256 blocks
    const int b   = bid & 7;                  // XCD k <-> batch k
    const int strip = bid >> 3;               // 0..31 (= it0 for every row)
    const int i0  = strip * 16;
    const int i   = i0 + w;
    const int lm = l & 15;
    const int lq = l >> 4;
    const unsigned short* __restrict__ Xg = Xb + (size_t)b * (512 * 64);
    const float* __restrict__ xi = x + ((size_t)b * 512 + i) * 64;

    // ---- A-fragments (W_i^T), pre-scaled by 2*log2(e) ----
    bf16x8 af[8];
    #pragma unroll
    for (int ks = 0; ks < 2; ++ks) {
        float4 xc0 = *(const float4*)(xi + ks * 32 + lq * 8);
        float4 xc1 = *(const float4*)(xi + ks * 32 + lq * 8 + 4);
        xc0.x *= C2LOG2E; xc0.y *= C2LOG2E; xc0.z *= C2LOG2E; xc0.w *= C2LOG2E;
        xc1.x *= C2LOG2E; xc1.y *= C2LOG2E; xc1.z *= C2LOG2E; xc1.w *= C2LOG2E;
        #pragma unroll
        for (int of = 0; of < 4; ++of) {
            const float* wr = Wt + (of * 16 + lm) * 64 + ks * 32 + lq * 8;
            float4 w0 = *(const float4*)(wr);
            float4 w1 = *(const float4*)(wr + 4);
            unsigned int p0 = f2bf(w0.x * xc0.x) | (f2bf(w0.y * xc0.y) << 16);
            unsigned int p1 = f2bf(w0.z * xc0.z) | (f2bf(w0.w * xc0.w) << 16);
            unsigned int p2 = f2bf(w1.x * xc1.x) | (f2bf(w1.y * xc1.y) << 16);
            unsigned int p3 = f2bf(w1.z * xc1.z) | (f2bf(w1.w * xc1.w) << 16);
            int4 pk = make_int4((int)p0, (int)p1, (int)p2, (int)p3);
            af[of * 2 + ks] = *reinterpret_cast<bf16x8*>(&pk);
        }
    }

    // ---- per-lane o-consts; bias folded into MFMA C-init ----
    float n2a[16];
    f32x4 binit[4];
    float asum = 0.f, aabs = 0.f;
    #pragma unroll
    for (int of = 0; of < 4; ++of) {
        #pragma unroll
        for (int r = 0; r < 4; ++r) {
            int o = of * 16 + lq * 4 + r;
            float a = att_w[o];
            n2a[of * 4 + r] = -2.f * a;
            binit[of][r]    = C2LOG2E * b_ap[o];
            asum += a;
            aabs += fabsf(a);
        }
    }
    asum += __shfl_xor(asum, 16); asum += __shfl_xor(asum, 32);
    aabs += __shfl_xor(aabs, 16); aabs += __shfl_xor(aabs, 32);
    const float coff = (asum - aabs) * LOG2E;  // e_j = exp2(ss*lg2e + coff)

    const int smax = (strip < 16) ? 17 : 16;
    unsigned short* __restrict__ Erow = E + ((size_t)b * 512 + i) * 512;
    unsigned short* __restrict__ Ecb  = E + (size_t)b * (512 * 512);
    const unsigned short* xrow = Xg + lm * 64 + lq * 8;

    for (int s = 0; s < smax; ++s) {
        const int jt = (strip + s) & 31;
        bf16x8 b0 = *(const bf16x8*)(xrow + jt * 1024);
        bf16x8 b1 = *(const bf16x8*)(xrow + jt * 1024 + 32);
        f32x4 a0 = binit[0], a1 = binit[1], a2 = binit[2], a3 = binit[3];
        a0 = __builtin_amdgcn_mfma_f32_16x16x32_bf16(af[0], b0, a0, 0, 0, 0);
        a1 = __builtin_amdgcn_mfma_f32_16x16x32_bf16(af[2], b0, a1, 0, 0, 0);
        a2 = __builtin_amdgcn_mfma_f32_16x16x32_bf16(af[4], b0, a2, 0, 0, 0);
        a3 = __builtin_amdgcn_mfma_f32_16x16x32_bf16(af[6], b0, a3, 0, 0, 0);
        a0 = __builtin_amdgcn_mfma_f32_16x16x32_bf16(af[1], b1, a0, 0, 0, 0);
        a1 = __builtin_amdgcn_mfma_f32_16x16x32_bf16(af[3], b1, a1, 0, 0, 0);
        a2 = __builtin_amdgcn_mfma_f32_16x16x32_bf16(af[5], b1, a2, 0, 0, 0);
        a3 = __builtin_amdgcn_mfma_f32_16x16x32_bf16(af[7], b1, a3, 0, 0, 0);
        // flattened trans chains: 16 indep exp2 -> 16 indep rcp -> fma tree
        float ex[16], tt[16];
        #pragma unroll
        for (int r = 0; r < 4; ++r) {
            ex[r]      = EXP2F(a0[r]);
            ex[4 + r]  = EXP2F(a1[r]);
            ex[8 + r]  = EXP2F(a2[r]);
            ex[12 + r] = EXP2F(a3[r]);
        }
        #pragma unroll
        for (int k = 0; k < 16; ++k) tt[k] = RCPF(1.f + ex[k]);
        float q0 = 0.f, q1 = 0.f, q2 = 0.f, q3 = 0.f;
        #pragma unroll
        for (int r = 0; r < 4; ++r) {
            q0 = fmaf(n2a[r],      tt[r],      q0);
            q1 = fmaf(n2a[4 + r],  tt[4 + r],  q1);
            q2 = fmaf(n2a[8 + r],  tt[8 + r],  q2);
            q3 = fmaf(n2a[12 + r], tt[12 + r], q3);
        }
        float ss = (q0 + q1) + (q2 + q3);
        ss += __shfl_xor(ss, 16);
        ss += __shfl_xor(ss, 32);              // all lanes: full ss for j=jt*16+lm
        float ee = EXP2F(fmaf(ss, LOG2E, coff));
        unsigned short eb = (unsigned short)f2bf(ee);
        if (l < 16) {
            Erow[jt * 16 + l] = eb;            // contiguous row write (32B/tile/wave)
            stage[s][l][w] = eb;               // mirror value -> LDS (no barrier)
        }
    }
    __syncthreads();                            // ONE barrier for the whole strip

    // ---- bulk mirror flush: E[j][i0..i0+15] as two 16B stores per j ----
    const int nm = smax - 1;                    // mirrored tiles (diag excluded)
    if (t < nm * 16) {
        int si = 1 + (t >> 4);                  // s = 1..nm
        int jl = t & 15;
        int jt = (strip + si) & 31;
        const unsigned short* sp = &stage[si][jl][0];
        int4 v0 = *(const int4*)(sp);
        int4 v1 = *(const int4*)(sp + 8);
        unsigned short* dst = Ecb + (size_t)(jt * 16 + jl) * 512 + i0;
        *(int4*)(dst)     = v0;
        *(int4*)(dst + 8) = v1;
    }
}

// ---- B: agg GEMM (E @ X) + projections + BN + SELU, all MFMA. ----
__global__ __launch_bounds__(256, 4) void agg_kernel(
    const unsigned short* __restrict__ Xb, const unsigned short* __restrict__ XT,
    const unsigned short* __restrict__ E,
    const unsigned short* __restrict__ Wpab, const unsigned short* __restrict__ Wpob,
    const float* __restrict__ bnA, const float* __restrict__ bnBB,
    float* __restrict__ out)
{
    __shared__ float sInv[16];
    __shared__ unsigned short pA[16][72];   // bf16 unnormalized agg, +8 pad

    const int t  = threadIdx.x;
    const int l  = t & 63;
    const int w  = t >> 6;
    const int bid = blockIdx.x;
    const int b   = bid & 7;                  // same XCD<->batch map: E, XT L2-hot
    const int i0  = (bid >> 3) * 16;
    const int lm = l & 15;
    const int lq = l >> 4;

    // ---- GEMM 1: acc[i-off][d-off] = sum_j E[i][j] * X[j][d], d-tile = w ----
    const unsigned short* Erow  = E  + ((size_t)b * 512 + i0 + lm) * 512 + lq * 8;
    const unsigned short* xtrow = XT + (size_t)b * (64 * 512) + (w * 16 + lm) * 512 + lq * 8;
    f32x4 acc = (f32x4){0.f, 0.f, 0.f, 0.f};
    float den = 0.f;
    #pragma unroll
    for (int jc = 0; jc < 16; ++jc) {
        bf16x8 ae = *(const bf16x8*)(Erow + jc * 32);
        bf16x8 bx = *(const bf16x8*)(xtrow + jc * 32);
        acc = __builtin_amdgcn_mfma_f32_16x16x32_bf16(ae, bx, acc, 0, 0, 0);
        if (w == 0) {
            #pragma unroll
            for (int e = 0; e < 8; ++e) den += bf2f((unsigned short)ae[e]);
        }
    }
    if (w == 0) {
        den += __shfl_xor(den, 16);
        den += __shfl_xor(den, 32);
        if (l < 16) sInv[l] = RCPF(den);
    }
    #pragma unroll
    for (int r = 0; r < 4; ++r)
        pA[lq * 4 + r][w * 16 + lm] = (unsigned short)f2bf(acc[r]);
    __syncthreads();

    // ---- GEMM 2: h = inv[i] * (aggU @ W_pa) + (x @ W_po); o-tile = w ----
    bf16x8 af2[2], afx[2], bwa[2], bwo[2];
    #pragma unroll
    for (int kc = 0; kc < 2; ++kc) {
        af2[kc] = *(const bf16x8*)(&pA[lm][kc * 32 + lq * 8]);
        afx[kc] = *(const bf16x8*)(Xb + ((size_t)b * 512 + i0 + lm) * 64 + kc * 32 + lq * 8);
        bwa[kc] = *(const bf16x8*)(Wpab + (w * 16 + lm) * 64 + kc * 32 + lq * 8);
        bwo[kc] = *(const bf16x8*)(Wpob + (w * 16 + lm) * 64 + kc * 32 + lq * 8);
    }
    f32x4 a2a = (f32x4){0.f, 0.f, 0.f, 0.f};
    f32x4 a2x = (f32x4){0.f, 0.f, 0.f, 0.f};
    a2a = __builtin_amdgcn_mfma_f32_16x16x32_bf16(af2[0], bwa[0], a2a, 0, 0, 0);
    a2x = __builtin_amdgcn_mfma_f32_16x16x32_bf16(afx[0], bwo[0], a2x, 0, 0, 0);
    a2a = __builtin_amdgcn_mfma_f32_16x16x32_bf16(af2[1], bwa[1], a2a, 0, 0, 0);
    a2x = __builtin_amdgcn_mfma_f32_16x16x32_bf16(afx[1], bwo[1], a2x, 0, 0, 0);

    // ---- epilogue: BN (biases folded) + SELU ----
    const int o = w * 16 + lm;
    const float A  = bnA[o];
    const float BB = bnBB[o];
    const float alpha = 1.6732632423543772f, scale = 1.0507009873554805f;
    #pragma unroll
    for (int r = 0; r < 4; ++r) {
        int i = i0 + lq * 4 + r;
        float hv = fmaf(sInv[lq * 4 + r], a2a[r], a2x[r]);
        hv = fmaf(hv, A, BB);
        float neg = alpha * (EXP2F(hv * LOG2E) - 1.0f);
        out[((size_t)b * 512 + i) * 64 + o] = scale * (hv > 0.f ? hv : neg);
    }
}

extern "C" void kernel_launch(void* const* d_in, const int* in_sizes, int n_in,
                              void* d_out, int out_size, void* d_ws, size_t ws_size,
                              hipStream_t stream) {
    const float* x     = (const float*)d_in[0];
    const float* W_ap  = (const float*)d_in[1];
    const float* b_ap  = (const float*)d_in[2];
    const float* att_w = (const float*)d_in[3];
    const float* W_pa  = (const float*)d_in[4];
    const float* b_pa  = (const float*)d_in[5];
    const float* W_po  = (const float*)d_in[6];
    const float* b_po  = (const float*)d_in[7];
    const float* gma   = (const float*)d_in[8];
    const float* bta   = (const float*)d_in[9];
    const float* rmean = (const float*)d_in[10];
    const float* rvar  = (const float*)d_in[11];

    char* ws = (char*)d_ws;
    unsigned short* Xb   = (unsigned short*)ws;                 // 512 KB bf16 X
    unsigned short* XT   = (unsigned short*)(ws + 512 * 1024);  // 512 KB bf16 X^T (d-major)
    float* Wt            = (float*)(ws + 1024 * 1024);          // 16 KB W_ap^T f32
    unsigned short* Wpab = (unsigned short*)(ws + 1040 * 1024); // 8 KB W_pa^T bf16
    unsigned short* Wpob = (unsigned short*)(ws + 1048 * 1024); // 8 KB W_po^T bf16
    float* bnA           = (float*)(ws + 1056 * 1024);          // 256 B
    float* bnBB          = (float*)(ws + 1057 * 1024);          // 256 B
    unsigned short* E    = (unsigned short*)(ws + 1088 * 1024); // 4 MB bf16 E[b][i][j]
    float* out           = (float*)d_out;

    prep_kernel<<<128, 256, 0, stream>>>(x, W_ap, W_pa, W_po, b_pa, b_po, gma, bta,
                                         rmean, rvar, Xb, XT, Wt, Wpab, Wpob, bnA, bnBB);
    score_kernel<<<256, 1024, 0, stream>>>(x, b_ap, att_w, Xb, Wt, E);
    agg_kernel<<<256, 256, 0, stream>>>(Xb, XT, E, Wpab, Wpob, bnA, bnBB, out);
}

// Round 24
// 45.138 us; speedup vs baseline: 1.2164x; 1.0003x over previous
//
#include <hip/hip_runtime.h>
#include <cstdint>

typedef __attribute__((ext_vector_type(8))) short bf16x8;
typedef __attribute__((ext_vector_type(4))) float f32x4;

#if __has_builtin(__builtin_amdgcn_exp2f)
#define EXP2F(x) __builtin_amdgcn_exp2f(x)
#else
#define EXP2F(x) exp2f(x)
#endif
#if __has_builtin(__builtin_amdgcn_rcpf)
#define RCPF(x) __builtin_amdgcn_rcpf(x)
#else
#define RCPF(x) (1.0f/(x))
#endif

#define C2LOG2E 2.885390081777927f   // 2*log2(e)
#define LOG2E   1.4426950408889634f

__device__ __forceinline__ unsigned int f2bf(float f) {
    union { float f; unsigned int u; } v; v.f = f;
    return ((v.u + 0x7FFFu + ((v.u >> 16) & 1u)) >> 16);
}
__device__ __forceinline__ float bf2f(unsigned short h) {
    union { unsigned int u; float f; } v; v.u = ((unsigned int)h) << 16; return v.f;
}

// ---- prep: Xb bf16; XT bf16 via LDS transpose (coalesced); W transposes; BN consts ----
__global__ void prep_kernel(const float* __restrict__ x, const float* __restrict__ W_ap,
                            const float* __restrict__ W_pa, const float* __restrict__ W_po,
                            const float* __restrict__ b_pa, const float* __restrict__ b_po,
                            const float* __restrict__ gma, const float* __restrict__ bta,
                            const float* __restrict__ rmean, const float* __restrict__ rvar,
                            unsigned short* __restrict__ Xb, unsigned short* __restrict__ XT,
                            float* __restrict__ Wt,
                            unsigned short* __restrict__ Wpab, unsigned short* __restrict__ Wpob,
                            float* __restrict__ bnA, float* __restrict__ bnBB) {
    __shared__ unsigned short sx[64][40];     // [d][jloc], padded rows (80B, 16B-aligned)
    int t = blockIdx.x * 256 + threadIdx.x;   // 32768 threads, 8 elems each
    const float* src = x + (size_t)t * 8;
    float4 a = *(const float4*)(src);
    float4 b = *(const float4*)(src + 4);
    unsigned int p0 = f2bf(a.x) | (f2bf(a.y) << 16);
    unsigned int p1 = f2bf(a.z) | (f2bf(a.w) << 16);
    unsigned int p2 = f2bf(b.x) | (f2bf(b.y) << 16);
    unsigned int p3 = f2bf(b.z) | (f2bf(b.w) << 16);
    *(int4*)(Xb + (size_t)t * 8) = make_int4((int)p0, (int)p1, (int)p2, (int)p3);
    // XT[b][d][j] via LDS tile: block = 32 j-rows of one batch
    {
        int tl = threadIdx.x;
        int jloc = tl >> 3, d0 = (tl & 7) * 8;
        unsigned short e8[8] = {(unsigned short)(p0 & 0xffff), (unsigned short)(p0 >> 16),
                                (unsigned short)(p1 & 0xffff), (unsigned short)(p1 >> 16),
                                (unsigned short)(p2 & 0xffff), (unsigned short)(p2 >> 16),
                                (unsigned short)(p3 & 0xffff), (unsigned short)(p3 >> 16)};
        #pragma unroll
        for (int e = 0; e < 8; ++e) sx[d0 + e][jloc] = e8[e];
        __syncthreads();
        int bb  = blockIdx.x >> 4;            // batch
        int jr0 = (blockIdx.x & 15) * 32;     // j-offset of this block
        int d   = tl >> 2, jo = (tl & 3) * 8;
        int4 v = *(const int4*)(&sx[d][jo]);
        *(int4*)(XT + (size_t)bb * (64 * 512) + (size_t)d * 512 + jr0 + jo) = v;
    }
    if (t < 64 * 64) {
        int src_i = (t & 63) * 64 + (t >> 6);   // [d][o] -> [o][d]
        Wt[t]   = W_ap[src_i];
        Wpab[t] = (unsigned short)f2bf(W_pa[src_i]);
        Wpob[t] = (unsigned short)f2bf(W_po[src_i]);
    }
    if (t < 64) {
        float A = gma[t] * rsqrtf(rvar[t] + 1e-5f);
        bnA[t]  = A;
        bnBB[t] = (b_pa[t] + b_po[t] - rmean[t]) * A + bta[t];
    }
}

// ---- A: scores, cyclic triangle, 16-row strips, barrier-free loop. Mirror
// values NEVER touch E: staged in LDS, bulk-flushed to compact M[b][c][s][jl][w]
// (bf16; 256 KB/XCD -> L2-resident; 512B-contiguous chunks). E gets only the
// direct window (contiguous row writes). agg reassembles rows from E + M.
__global__ __launch_bounds__(1024, 1) void score_kernel(
    const float* __restrict__ x, const float* __restrict__ b_ap, const float* __restrict__ att_w,
    const unsigned short* __restrict__ Xb, const float* __restrict__ Wt,
    unsigned short* __restrict__ E, unsigned short* __restrict__ M)
{
    __shared__ unsigned short stage[17][16][16];   // [s][jl][w] = 8.7 KB

    const int t  = threadIdx.x;
    const int l  = t & 63;
    const int w  = t >> 6;                    // 0..15 = row within strip
    const int bid = blockIdx.x;               // 256 blocks
    const int b   = bid & 7;                  // XCD k <-> batch k
    const int strip = bid >> 3;               // 0..31 (= it0 for every row)
    const int i0  = strip * 16;
    const int i   = i0 + w;
    const int lm = l & 15;
    const int lq = l >> 4;
    const unsigned short* __restrict__ Xg = Xb + (size_t)b * (512 * 64);
    const float* __restrict__ xi = x + ((size_t)b * 512 + i) * 64;

    // ---- A-fragments (W_i^T), pre-scaled by 2*log2(e) ----
    bf16x8 af[8];
    #pragma unroll
    for (int ks = 0; ks < 2; ++ks) {
        float4 xc0 = *(const float4*)(xi + ks * 32 + lq * 8);
        float4 xc1 = *(const float4*)(xi + ks * 32 + lq * 8 + 4);
        xc0.x *= C2LOG2E; xc0.y *= C2LOG2E; xc0.z *= C2LOG2E; xc0.w *= C2LOG2E;
        xc1.x *= C2LOG2E; xc1.y *= C2LOG2E; xc1.z *= C2LOG2E; xc1.w *= C2LOG2E;
        #pragma unroll
        for (int of = 0; of < 4; ++of) {
            const float* wr = Wt + (of * 16 + lm) * 64 + ks * 32 + lq * 8;
            float4 w0 = *(const float4*)(wr);
            float4 w1 = *(const float4*)(wr + 4);
            unsigned int p0 = f2bf(w0.x * xc0.x) | (f2bf(w0.y * xc0.y) << 16);
            unsigned int p1 = f2bf(w0.z * xc0.z) | (f2bf(w0.w * xc0.w) << 16);
            unsigned int p2 = f2bf(w1.x * xc1.x) | (f2bf(w1.y * xc1.y) << 16);
            unsigned int p3 = f2bf(w1.z * xc1.z) | (f2bf(w1.w * xc1.w) << 16);
            int4 pk = make_int4((int)p0, (int)p1, (int)p2, (int)p3);
            af[of * 2 + ks] = *reinterpret_cast<bf16x8*>(&pk);
        }
    }

    // ---- per-lane o-consts; bias folded into MFMA C-init ----
    float n2a[16];
    f32x4 binit[4];
    float asum = 0.f, aabs = 0.f;
    #pragma unroll
    for (int of = 0; of < 4; ++of) {
        #pragma unroll
        for (int r = 0; r < 4; ++r) {
            int o = of * 16 + lq * 4 + r;
            float a = att_w[o];
            n2a[of * 4 + r] = -2.f * a;
            binit[of][r]    = C2LOG2E * b_ap[o];
            asum += a;
            aabs += fabsf(a);
        }
    }
    asum += __shfl_xor(asum, 16); asum += __shfl_xor(asum, 32);
    aabs += __shfl_xor(aabs, 16); aabs += __shfl_xor(aabs, 32);
    const float coff = (asum - aabs) * LOG2E;  // e_j = exp2(ss*lg2e + coff)

    const int smax = (strip < 16) ? 17 : 16;
    unsigned short* __restrict__ Erow = E + ((size_t)b * 512 + i) * 512;
    const unsigned short* xrow = Xg + lm * 64 + lq * 8;

    for (int s = 0; s < smax; ++s) {
        const int jt = (strip + s) & 31;
        bf16x8 b0 = *(const bf16x8*)(xrow + jt * 1024);
        bf16x8 b1 = *(const bf16x8*)(xrow + jt * 1024 + 32);
        f32x4 a0 = binit[0], a1 = binit[1], a2 = binit[2], a3 = binit[3];
        a0 = __builtin_amdgcn_mfma_f32_16x16x32_bf16(af[0], b0, a0, 0, 0, 0);
        a1 = __builtin_amdgcn_mfma_f32_16x16x32_bf16(af[2], b0, a1, 0, 0, 0);
        a2 = __builtin_amdgcn_mfma_f32_16x16x32_bf16(af[4], b0, a2, 0, 0, 0);
        a3 = __builtin_amdgcn_mfma_f32_16x16x32_bf16(af[6], b0, a3, 0, 0, 0);
        a0 = __builtin_amdgcn_mfma_f32_16x16x32_bf16(af[1], b1, a0, 0, 0, 0);
        a1 = __builtin_amdgcn_mfma_f32_16x16x32_bf16(af[3], b1, a1, 0, 0, 0);
        a2 = __builtin_amdgcn_mfma_f32_16x16x32_bf16(af[5], b1, a2, 0, 0, 0);
        a3 = __builtin_amdgcn_mfma_f32_16x16x32_bf16(af[7], b1, a3, 0, 0, 0);
        // flattened trans chains: 16 indep exp2 -> 16 indep rcp -> fma tree
        float ex[16], tt[16];
        #pragma unroll
        for (int r = 0; r < 4; ++r) {
            ex[r]      = EXP2F(a0[r]);
            ex[4 + r]  = EXP2F(a1[r]);
            ex[8 + r]  = EXP2F(a2[r]);
            ex[12 + r] = EXP2F(a3[r]);
        }
        #pragma unroll
        for (int k = 0; k < 16; ++k) tt[k] = RCPF(1.f + ex[k]);
        float q0 = 0.f, q1 = 0.f, q2 = 0.f, q3 = 0.f;
        #pragma unroll
        for (int r = 0; r < 4; ++r) {
            q0 = fmaf(n2a[r],      tt[r],      q0);
            q1 = fmaf(n2a[4 + r],  tt[4 + r],  q1);
            q2 = fmaf(n2a[8 + r],  tt[8 + r],  q2);
            q3 = fmaf(n2a[12 + r], tt[12 + r], q3);
        }
        float ss = (q0 + q1) + (q2 + q3);
        ss += __shfl_xor(ss, 16);
        ss += __shfl_xor(ss, 32);              // all lanes: full ss for j=jt*16+lm
        float ee = EXP2F(fmaf(ss, LOG2E, coff));
        unsigned short eb = (unsigned short)f2bf(ee);
        if (l < 16) {
            Erow[jt * 16 + l] = eb;            // direct (contiguous row write)
            stage[s][l][w] = eb;               // mirror value -> LDS
        }
    }
    __syncthreads();                            // ONE barrier for the whole strip

    // ---- bulk mirror flush -> compact M[b][strip][s-1][jl][0..15] (512B chunks) ----
    const int nm = smax - 1;
    if (t < nm * 16) {
        int si = 1 + (t >> 4);                  // s = 1..nm
        int jl = t & 15;
        const unsigned short* sp = &stage[si][jl][0];
        int4 v0 = *(const int4*)(sp);
        int4 v1 = *(const int4*)(sp + 8);
        unsigned short* dst = M + ((((size_t)(b * 32 + strip) * 16) + (si - 1)) * 16 + jl) * 16;
        *(int4*)(dst)     = v0;
        *(int4*)(dst + 8) = v1;
    }
}

// ---- B: agg GEMM (E/M @ X) + projections + BN + SELU, all MFMA.
// A-fragment group g (16 cols) of row-strip Sr: direct iff ((g-Sr)&31)<smax_r
// (read E); else mirror chunk M[b][g][(Sr-g)&31 - 1][lm][..] (16B/lane). ----
__global__ __launch_bounds__(256, 4) void agg_kernel(
    const unsigned short* __restrict__ Xb, const unsigned short* __restrict__ XT,
    const unsigned short* __restrict__ E, const unsigned short* __restrict__ M,
    const unsigned short* __restrict__ Wpab, const unsigned short* __restrict__ Wpob,
    const float* __restrict__ bnA, const float* __restrict__ bnBB,
    float* __restrict__ out)
{
    __shared__ float sInv[16];
    __shared__ unsigned short pA[16][72];   // bf16 unnormalized agg, +8 pad

    const int t  = threadIdx.x;
    const int l  = t & 63;
    const int w  = t >> 6;
    const int bid = blockIdx.x;
    const int b   = bid & 7;                  // same XCD<->batch map: E, M, XT L2-hot
    const int i0  = (bid >> 3) * 16;
    const int lm = l & 15;
    const int lq = l >> 4;
    const int Sr = i0 >> 4;
    const int smax_r = (Sr < 16) ? 17 : 16;

    // ---- GEMM 1: acc[i-off][d-off] = sum_j E[i][j] * X[j][d], d-tile = w ----
    const unsigned short* Ebase = E + ((size_t)b * 512 + i0 + lm) * 512 + (lq & 1) * 8;
    const unsigned short* Mbase = M + (size_t)b * (32 * 16 * 16 * 16) + lm * 16 + (lq & 1) * 8;
    const unsigned short* xtrow = XT + (size_t)b * (64 * 512) + (w * 16 + lm) * 512 + lq * 8;
    f32x4 acc = (f32x4){0.f, 0.f, 0.f, 0.f};
    float den = 0.f;
    #pragma unroll
    for (int jc = 0; jc < 16; ++jc) {
        int g   = 2 * jc + (lq >> 1);          // 16-col group for this lane
        int del = (g - Sr) & 31;
        int s   = (Sr - g) & 31;               // mirror source tile (1..16 when used)
        const unsigned short* pa = (del < smax_r)
            ? Ebase + g * 16
            : Mbase + (((size_t)g * 16) + (s - 1)) * 256;
        bf16x8 ae = *(const bf16x8*)pa;
        bf16x8 bx = *(const bf16x8*)(xtrow + jc * 32);
        acc = __builtin_amdgcn_mfma_f32_16x16x32_bf16(ae, bx, acc, 0, 0, 0);
        if (w == 0) {
            #pragma unroll
            for (int e = 0; e < 8; ++e) den += bf2f((unsigned short)ae[e]);
        }
    }
    if (w == 0) {
        den += __shfl_xor(den, 16);
        den += __shfl_xor(den, 32);
        if (l < 16) sInv[l] = RCPF(den);
    }
    #pragma unroll
    for (int r = 0; r < 4; ++r)
        pA[lq * 4 + r][w * 16 + lm] = (unsigned short)f2bf(acc[r]);
    __syncthreads();

    // ---- GEMM 2: h = inv[i] * (aggU @ W_pa) + (x @ W_po); o-tile = w ----
    bf16x8 af2[2], afx[2], bwa[2], bwo[2];
    #pragma unroll
    for (int kc = 0; kc < 2; ++kc) {
        af2[kc] = *(const bf16x8*)(&pA[lm][kc * 32 + lq * 8]);
        afx[kc] = *(const bf16x8*)(Xb + ((size_t)b * 512 + i0 + lm) * 64 + kc * 32 + lq * 8);
        bwa[kc] = *(const bf16x8*)(Wpab + (w * 16 + lm) * 64 + kc * 32 + lq * 8);
        bwo[kc] = *(const bf16x8*)(Wpob + (w * 16 + lm) * 64 + kc * 32 + lq * 8);
    }
    f32x4 a2a = (f32x4){0.f, 0.f, 0.f, 0.f};
    f32x4 a2x = (f32x4){0.f, 0.f, 0.f, 0.f};
    a2a = __builtin_amdgcn_mfma_f32_16x16x32_bf16(af2[0], bwa[0], a2a, 0, 0, 0);
    a2x = __builtin_amdgcn_mfma_f32_16x16x32_bf16(afx[0], bwo[0], a2x, 0, 0, 0);
    a2a = __builtin_amdgcn_mfma_f32_16x16x32_bf16(af2[1], bwa[1], a2a, 0, 0, 0);
    a2x = __builtin_amdgcn_mfma_f32_16x16x32_bf16(afx[1], bwo[1], a2x, 0, 0, 0);

    // ---- epilogue: BN (biases folded) + SELU ----
    const int o = w * 16 + lm;
    const float A  = bnA[o];
    const float BB = bnBB[o];
    const float alpha = 1.6732632423543772f, scale = 1.0507009873554805f;
    #pragma unroll
    for (int r = 0; r < 4; ++r) {
        int i = i0 + lq * 4 + r;
        float hv = fmaf(sInv[lq * 4 + r], a2a[r], a2x[r]);
        hv = fmaf(hv, A, BB);
        float neg = alpha * (EXP2F(hv * LOG2E) - 1.0f);
        out[((size_t)b * 512 + i) * 64 + o] = scale * (hv > 0.f ? hv : neg);
    }
}

extern "C" void kernel_launch(void* const* d_in, const int* in_sizes, int n_in,
                              void* d_out, int out_size, void* d_ws, size_t ws_size,
                              hipStream_t stream) {
    const float* x     = (const float*)d_in[0];
    const float* W_ap  = (const float*)d_in[1];
    const float* b_ap  = (const float*)d_in[2];
    const float* att_w = (const float*)d_in[3];
    const float* W_pa  = (const float*)d_in[4];
    const float* b_pa  = (const float*)d_in[5];
    const float* W_po  = (const float*)d_in[6];
    const float* b_po  = (const float*)d_in[7];
    const float* gma   = (const float*)d_in[8];
    const float* bta   = (const float*)d_in[9];
    const float* rmean = (const float*)d_in[10];
    const float* rvar  = (const float*)d_in[11];

    char* ws = (char*)d_ws;
    unsigned short* Xb   = (unsigned short*)ws;                 // 512 KB bf16 X
    unsigned short* XT   = (unsigned short*)(ws + 512 * 1024);  // 512 KB bf16 X^T (d-major)
    float* Wt            = (float*)(ws + 1024 * 1024);          // 16 KB W_ap^T f32
    unsigned short* Wpab = (unsigned short*)(ws + 1040 * 1024); // 8 KB W_pa^T bf16
    unsigned short* Wpob = (unsigned short*)(ws + 1048 * 1024); // 8 KB W_po^T bf16
    float* bnA           = (float*)(ws + 1056 * 1024);          // 256 B
    float* bnBB          = (float*)(ws + 1057 * 1024);          // 256 B
    unsigned short* E    = (unsigned short*)(ws + 1088 * 1024); // 4 MB bf16 E (direct half)
    unsigned short* M    = (unsigned short*)(ws + 5184 * 1024); // 2 MB bf16 mirror chunks
    float* out           = (float*)d_out;

    prep_kernel<<<128, 256, 0, stream>>>(x, W_ap, W_pa, W_po, b_pa, b_po, gma, bta,
                                         rmean, rvar, Xb, XT, Wt, Wpab, Wpob, bnA, bnBB);
    score_kernel<<<256, 1024, 0, stream>>>(x, b_ap, att_w, Xb, Wt, E, M);
    agg_kernel<<<256, 256, 0, stream>>>(Xb, XT, E, M, Wpab, Wpob, bnA, bnBB, out);
}